// Round 1
// baseline (134.088 us; speedup 1.0000x reference)
//
#include <hip/hip_runtime.h>

// Problem constants (from reference setup_inputs): B=8, N=16384, K=64
#define BB 8
#define NN 16384
#define KK 64

// SIGMA = 0.2 -> inv = -1/(2*sigma^2) = -12.5 ; -2*inv = 25
__constant__ const float F_INV = -12.5f;
__constant__ const float F_M2INV = 25.0f;

// Kernel 1: per-point feature computation + fused per-k sum/sumsq reduction.
// One thread per (b,n). Block = 256 threads (4 waves).
__global__ __launch_bounds__(256) void fkc_main(
    const float* __restrict__ normals,   // (B,3,N)
    const int*   __restrict__ nidx,      // (B,N,3) int32
    const float* __restrict__ walpha,    // (1,K,4)
    const float* __restrict__ wbeta,     // (1,K,4)
    float* __restrict__ out,             // (B,K,N) feat (pre-BN)
    float* __restrict__ gsum,            // (K,)
    float* __restrict__ gss)             // (K,)
{
    __shared__ float Wx[KK * 4], Wy[KK * 4], Wz[KK * 4];
    __shared__ float psum[KK][4];
    __shared__ float pss[KK][4];

    const int tid = threadIdx.x;

    // Build W in LDS: thread t handles (k = t/4, m = t%4); flat idx == t.
    {
        float a = walpha[tid];
        float b = wbeta[tid];
        float sa = __sinf(a);
        Wx[tid] = sa * __cosf(b);
        Wy[tid] = sa * __sinf(b);
        Wz[tid] = __cosf(a);
    }
    __syncthreads();

    const int gid = blockIdx.x * 256 + tid;
    const int b = gid >> 14;          // / NN
    const int n = gid & (NN - 1);     // % NN
    const float* nb = normals + b * 3 * NN;

    // Gather the 4 face points (center + 3 neighbors), all unit normals.
    float fx[4], fy[4], fz[4], e[4];
    fx[0] = nb[n];
    fy[0] = nb[NN + n];
    fz[0] = nb[2 * NN + n];
    const int ibase = (b * NN + n) * 3;
#pragma unroll
    for (int j = 0; j < 3; ++j) {
        int id = nidx[ibase + j];
        fx[j + 1] = nb[id];
        fy[j + 1] = nb[NN + id];
        fz[j + 1] = nb[2 * NN + id];
    }
#pragma unroll
    for (int p = 0; p < 4; ++p) {
        float n2 = fmaf(fx[p], fx[p], fmaf(fy[p], fy[p], fz[p] * fz[p]));
        // dist = n2 + ||w||^2 - 2 dot ; ||w||^2 == 1 exactly (unit sphere).
        e[p] = F_INV * (n2 + 1.0f);   // k-independent part of inv*dist
    }

    const int lane = tid & 63;
    const int wv = tid >> 6;

    for (int k = 0; k < KK; ++k) {
        float acc = 0.0f;
#pragma unroll
        for (int m = 0; m < 4; ++m) {
            float wx = Wx[k * 4 + m];
            float wy = Wy[k * 4 + m];
            float wz = Wz[k * 4 + m];
#pragma unroll
            for (int p = 0; p < 4; ++p) {
                float d = fmaf(fx[p], wx, fmaf(fy[p], wy, fz[p] * wz));
                acc += __expf(fmaf(F_M2INV, d, e[p]));
            }
        }
        float feat = acc * (1.0f / 16.0f);
        out[(b * KK + k) * NN + n] = feat;

        // 64-lane butterfly reduction of (sum, sumsq) for this k.
        float s = feat;
        float ss = feat * feat;
#pragma unroll
        for (int off = 1; off < 64; off <<= 1) {
            s  += __shfl_xor(s,  off, 64);
            ss += __shfl_xor(ss, off, 64);
        }
        if (lane == 0) { psum[k][wv] = s; pss[k][wv] = ss; }
    }
    __syncthreads();

    if (tid < KK) {
        float s  = psum[tid][0] + psum[tid][1] + psum[tid][2] + psum[tid][3];
        float ss = pss[tid][0] + pss[tid][1] + pss[tid][2] + pss[tid][3];
        atomicAdd(&gsum[tid], s);
        atomicAdd(&gss[tid], ss);
    }
}

// Kernel 2: fold sums into per-k BN scale/shift.
__global__ __launch_bounds__(64) void fkc_stats(
    const float* __restrict__ gsum,
    const float* __restrict__ gss,
    const float* __restrict__ gamma,
    const float* __restrict__ beta,
    float* __restrict__ scale,
    float* __restrict__ shift)
{
    const int k = threadIdx.x;
    const float invM = 1.0f / (float)(BB * NN);
    float mean = gsum[k] * invM;
    float var = fmaf(-mean, mean, gss[k] * invM);   // biased variance
    float sc = gamma[k] * rsqrtf(var + 1e-5f);
    scale[k] = sc;
    shift[k] = fmaf(-mean, sc, beta[k]);
}

// Kernel 3: in-place BN + ReLU on d_out, float4-vectorized.
// N/4 = 4096 float4 per (b,k) row -> k = (i >> 12) & 63.
__global__ __launch_bounds__(256) void fkc_apply(
    float4* __restrict__ out4,
    const float* __restrict__ scale,
    const float* __restrict__ shift)
{
    const int i = blockIdx.x * 256 + threadIdx.x;   // 0 .. 2097151
    const int k = (i >> 12) & (KK - 1);
    const float sc = scale[k];
    const float sh = shift[k];
    float4 v = out4[i];
    v.x = fmaxf(fmaf(v.x, sc, sh), 0.0f);
    v.y = fmaxf(fmaf(v.y, sc, sh), 0.0f);
    v.z = fmaxf(fmaf(v.z, sc, sh), 0.0f);
    v.w = fmaxf(fmaf(v.w, sc, sh), 0.0f);
    out4[i] = v;
}

extern "C" void kernel_launch(void* const* d_in, const int* in_sizes, int n_in,
                              void* d_out, int out_size, void* d_ws, size_t ws_size,
                              hipStream_t stream) {
    const float* normals = (const float*)d_in[0];
    const int*   nidx    = (const int*)d_in[1];
    const float* walpha  = (const float*)d_in[2];
    const float* wbeta   = (const float*)d_in[3];
    const float* gamma   = (const float*)d_in[4];
    const float* beta    = (const float*)d_in[5];
    float* out = (float*)d_out;
    float* ws = (float*)d_ws;

    float* gsum  = ws;          // [64]
    float* gss   = ws + 64;     // [64]
    float* scale = ws + 128;    // [64]
    float* shift = ws + 192;    // [64]

    // gsum/gss must start at zero (ws is poisoned 0xAA before every launch).
    hipMemsetAsync(ws, 0, 128 * sizeof(float), stream);

    const int total = BB * NN;                 // 131072 points
    fkc_main<<<total / 256, 256, 0, stream>>>(normals, nidx, walpha, wbeta,
                                              out, gsum, gss);
    fkc_stats<<<1, 64, 0, stream>>>(gsum, gss, gamma, beta, scale, shift);

    const int n4 = (BB * KK * NN) / 4;         // 2097152 float4
    fkc_apply<<<n4 / 256, 256, 0, stream>>>((float4*)out, scale, shift);
}

// Round 2
// 118.844 us; speedup vs baseline: 1.1283x; 1.1283x over previous
//
#include <hip/hip_runtime.h>

// Problem constants (from reference setup_inputs): B=8, N=16384, K=64
#define BB 8
#define NN 16384
#define KK 64

#if __has_builtin(__builtin_amdgcn_exp2f)
#define EXP2(x) __builtin_amdgcn_exp2f(x)
#else
#define EXP2(x) exp2f(x)
#endif

#define LOG2E 1.44269504088896340736f
// arg = log2e * (-12.5) * (dist) ; dist = n2 + 1 - 2*dot
// => arg = (25*log2e)*dot + (-12.5*log2e)*(n2+1)
#define CW (25.0f * LOG2E)
#define CE (-12.5f * LOG2E)

// ---------------------------------------------------------------------------
// Kernel 1: per-point feature computation. One thread per (b,n) x half-of-k.
// Grid = 1024 blocks (512 point-groups x 2 k-halves), block = 256 threads.
// Writes feat (scaled by 16 vs reference -- BN is scale-invariant) to out.
// ---------------------------------------------------------------------------
__global__ __launch_bounds__(256) void fkc_main(
    const float* __restrict__ normals,   // (B,3,N)
    const int*   __restrict__ nidx,      // (B,N,3) int32
    const float* __restrict__ walpha,    // (1,K,4)
    const float* __restrict__ wbeta,     // (1,K,4)
    float* __restrict__ out)             // (B,K,N) feat (pre-BN, x16)
{
    __shared__ float4 WV[KK * 4];        // (wx', wy', wz', 0) scaled by 25*log2e

    const int tid = threadIdx.x;

    // Build W in LDS: thread t handles (k = t/4, m = t%4); flat idx == t.
    {
        float a = walpha[tid];
        float b = wbeta[tid];
        float sa = __sinf(a);
        WV[tid] = make_float4(CW * sa * __cosf(b),
                              CW * sa * __sinf(b),
                              CW * __cosf(a), 0.0f);
    }
    __syncthreads();

    const int pg = blockIdx.x >> 1;          // point group 0..511
    const int k0 = (blockIdx.x & 1) * 32;    // k half
    const int gid = pg * 256 + tid;
    const int b = gid >> 14;                 // / NN
    const int n = gid & (NN - 1);            // % NN
    const float* nb = normals + b * 3 * NN;

    // Gather the 4 face points (center + 3 neighbors).
    float fx[4], fy[4], fz[4], e2[4];
    fx[0] = nb[n];
    fy[0] = nb[NN + n];
    fz[0] = nb[2 * NN + n];
    const int ibase = (b * NN + n) * 3;
#pragma unroll
    for (int j = 0; j < 3; ++j) {
        int id = nidx[ibase + j];
        fx[j + 1] = nb[id];
        fy[j + 1] = nb[NN + id];
        fz[j + 1] = nb[2 * NN + id];
    }
#pragma unroll
    for (int p = 0; p < 4; ++p) {
        float n2 = fmaf(fx[p], fx[p], fmaf(fy[p], fy[p], fz[p] * fz[p]));
        e2[p] = CE * (n2 + 1.0f);            // k-independent part of log2(exp term)
    }

    float* orow = out + (b * KK + k0) * NN + n;
#pragma unroll 2
    for (int k = 0; k < 32; ++k) {
        float acc = 0.0f;
#pragma unroll
        for (int m = 0; m < 4; ++m) {
            float4 w = WV[((k0 + k) << 2) + m];
#pragma unroll
            for (int p = 0; p < 4; ++p) {
                float arg = fmaf(fz[p], w.z,
                            fmaf(fy[p], w.y,
                            fmaf(fx[p], w.x, e2[p])));
                acc += EXP2(arg);
            }
        }
        orow[k * NN] = acc;
    }
}

// ---------------------------------------------------------------------------
// Kernel 2: per-k partial sums of (feat, feat^2). Grid = 64 k x 16 chunks.
// Chunk c: b = c>>1, half = c&1 -> 8192 consecutive floats of row (b,k).
// Writes ws[k*16+c] (sum) and ws[1024 + k*16+c] (sumsq). No atomics.
// ---------------------------------------------------------------------------
__global__ __launch_bounds__(256) void fkc_reduce(
    const float4* __restrict__ out4,
    float* __restrict__ psum,            // [1024]
    float* __restrict__ pss)             // [1024]
{
    __shared__ float sw[4], ssw[4];
    const int tid = threadIdx.x;
    const int k = blockIdx.x >> 4;
    const int c = blockIdx.x & 15;
    const int b = c >> 1;
    const int half = c & 1;
    const int base4 = (b * KK + k) * (NN / 4) + half * 2048;

    float s = 0.0f, ss = 0.0f;
#pragma unroll
    for (int i = 0; i < 8; ++i) {
        float4 v = out4[base4 + tid + i * 256];
        s += v.x + v.y + v.z + v.w;
        ss += fmaf(v.x, v.x, fmaf(v.y, v.y, fmaf(v.z, v.z, v.w * v.w)));
    }
#pragma unroll
    for (int off = 1; off < 64; off <<= 1) {
        s  += __shfl_xor(s,  off, 64);
        ss += __shfl_xor(ss, off, 64);
    }
    const int wv = tid >> 6;
    if ((tid & 63) == 0) { sw[wv] = s; ssw[wv] = ss; }
    __syncthreads();
    if (tid == 0) {
        psum[blockIdx.x] = sw[0] + sw[1] + sw[2] + sw[3];
        pss[blockIdx.x]  = ssw[0] + ssw[1] + ssw[2] + ssw[3];
    }
}

// ---------------------------------------------------------------------------
// Kernel 3: BN + ReLU in place. Each block covers 256 float4 within a single
// k stripe (4096 float4 per (b,k) row, 16 blocks per row -> k uniform).
// Folds the 16 partials into mean/var locally (32 loads per block).
// ---------------------------------------------------------------------------
__global__ __launch_bounds__(256) void fkc_apply(
    float4* __restrict__ out4,
    const float* __restrict__ psum,
    const float* __restrict__ pss,
    const float* __restrict__ gamma,
    const float* __restrict__ beta)
{
    __shared__ float s_tot, ss_tot;
    const int tid = threadIdx.x;
    const int i = blockIdx.x * 256 + tid;
    const int k = (i >> 12) & (KK - 1);      // uniform within block

    if (tid < 32) {
        float v = (tid < 16) ? psum[k * 16 + tid] : pss[k * 16 + (tid - 16)];
#pragma unroll
        for (int off = 1; off < 16; off <<= 1) v += __shfl_xor(v, off, 64);
        if (tid == 0)  s_tot = v;
        if (tid == 16) ss_tot = v;
    }
    __syncthreads();

    const float invM = 1.0f / (float)(BB * NN);
    float mean = s_tot * invM;
    float var = fmaf(-mean, mean, ss_tot * invM);   // biased variance
    float sc = gamma[k] * rsqrtf(var + 1e-5f);
    float sh = fmaf(-mean, sc, beta[k]);

    float4 v = out4[i];
    v.x = fmaxf(fmaf(v.x, sc, sh), 0.0f);
    v.y = fmaxf(fmaf(v.y, sc, sh), 0.0f);
    v.z = fmaxf(fmaf(v.z, sc, sh), 0.0f);
    v.w = fmaxf(fmaf(v.w, sc, sh), 0.0f);
    out4[i] = v;
}

extern "C" void kernel_launch(void* const* d_in, const int* in_sizes, int n_in,
                              void* d_out, int out_size, void* d_ws, size_t ws_size,
                              hipStream_t stream) {
    const float* normals = (const float*)d_in[0];
    const int*   nidx    = (const int*)d_in[1];
    const float* walpha  = (const float*)d_in[2];
    const float* wbeta   = (const float*)d_in[3];
    const float* gamma   = (const float*)d_in[4];
    const float* beta    = (const float*)d_in[5];
    float* out = (float*)d_out;
    float* ws = (float*)d_ws;

    float* psum = ws;           // [1024]
    float* pss  = ws + 1024;    // [1024]

    fkc_main<<<1024, 256, 0, stream>>>(normals, nidx, walpha, wbeta, out);
    fkc_reduce<<<1024, 256, 0, stream>>>((const float4*)out, psum, pss);
    fkc_apply<<<8192, 256, 0, stream>>>((float4*)out, psum, pss, gamma, beta);
}

// Round 4
// 118.093 us; speedup vs baseline: 1.1354x; 1.0064x over previous
//
#include <hip/hip_runtime.h>

// Problem constants (from reference setup_inputs): B=8, N=16384, K=64
#define BB 8
#define NN 16384
#define KK 64
#define NPG 512          // point groups (B*N / 256)

#if __has_builtin(__builtin_amdgcn_exp2f)
#define EXP2(x) __builtin_amdgcn_exp2f(x)
#else
#define EXP2(x) exp2f(x)
#endif

#define LOG2E 1.44269504088896340736f
// exp(inv*dist) = exp2( CW*dot + CE*(n2+1) ), inv = -12.5, ||w||^2 == 1
#define CW (25.0f * LOG2E)
#define CE (-12.5f * LOG2E)

// ---------------------------------------------------------------------------
// Kernel 0: precompute scaled kernel directions into global SoA buffers so
// the hot loop reads them with wave-uniform indices (s_load, no LDS/lgkm).
// ---------------------------------------------------------------------------
__global__ __launch_bounds__(256) void fkc_prep(
    const float* __restrict__ walpha,    // (1,K,4)
    const float* __restrict__ wbeta,     // (1,K,4)
    float* __restrict__ wx,              // [256]
    float* __restrict__ wy,              // [256]
    float* __restrict__ wz)              // [256]
{
    const int t = threadIdx.x;
    float a = walpha[t];
    float b = wbeta[t];
    float sa = __sinf(a);
    wx[t] = CW * sa * __cosf(b);
    wy[t] = CW * sa * __sinf(b);
    wz[t] = CW * __cosf(a);
}

// ---------------------------------------------------------------------------
// Kernel 1: per-point features + fused per-k (sum, sumsq) partials.
// Grid = 2048 blocks (512 point-groups x 4 k-quarters), block = 256.
// feat kept at 16x reference scale (BN is scale-invariant).
// ---------------------------------------------------------------------------
__global__ __launch_bounds__(256, 8) void fkc_main(
    const float* __restrict__ normals,   // (B,3,N)
    const int*   __restrict__ nidx,      // (B,N,3) int32
    const float* __restrict__ wx,        // [256] wave-uniform reads
    const float* __restrict__ wy,
    const float* __restrict__ wz,
    float* __restrict__ out,             // (B,K,N) feat (pre-BN, x16)
    float* __restrict__ psum,            // [KK*NPG]
    float* __restrict__ pss)             // [KK*NPG]
{
    __shared__ float reds[16][4];
    __shared__ float redss[16][4];

    const int tid = threadIdx.x;
    const int pg = blockIdx.x >> 2;          // point group 0..511
    const int k0 = (blockIdx.x & 3) * 16;    // k quarter
    const int gid = pg * 256 + tid;
    const int b = gid >> 14;
    const int n = gid & (NN - 1);
    const float* nb = normals + b * 3 * NN;

    // Gather the 4 face points (center + 3 neighbors), all unit normals.
    float fx[4], fy[4], fz[4], e2[4];
    fx[0] = nb[n];
    fy[0] = nb[NN + n];
    fz[0] = nb[2 * NN + n];
    const int ibase = (b * NN + n) * 3;
#pragma unroll
    for (int j = 0; j < 3; ++j) {
        int id = nidx[ibase + j];
        fx[j + 1] = nb[id];
        fy[j + 1] = nb[NN + id];
        fz[j + 1] = nb[2 * NN + id];
    }
#pragma unroll
    for (int p = 0; p < 4; ++p) {
        float n2 = fmaf(fx[p], fx[p], fmaf(fy[p], fy[p], fz[p] * fz[p]));
        e2[p] = CE * (n2 + 1.0f);
    }

    const int lane = tid & 63;
    const int wv = tid >> 6;
    float* orow = out + (b * KK + k0) * NN + n;

#pragma unroll
    for (int kk = 0; kk < 16; ++kk) {
        float acc = 0.0f;
#pragma unroll
        for (int m = 0; m < 4; ++m) {
            const int wi = ((k0 + kk) << 2) + m;   // wave-uniform -> s_load
            float wxv = wx[wi], wyv = wy[wi], wzv = wz[wi];
#pragma unroll
            for (int p = 0; p < 4; ++p) {
                float arg = fmaf(fz[p], wzv,
                            fmaf(fy[p], wyv,
                            fmaf(fx[p], wxv, e2[p])));
                acc += EXP2(arg);
            }
        }
        orow[kk * NN] = acc;

        float s = acc, ss = acc * acc;
#pragma unroll
        for (int off = 1; off < 64; off <<= 1) {
            s  += __shfl_xor(s,  off, 64);
            ss += __shfl_xor(ss, off, 64);
        }
        if (lane == 0) { reds[kk][wv] = s; redss[kk][wv] = ss; }
    }
    __syncthreads();

    if (tid < 16) {
        psum[(k0 + tid) * NPG + pg] =
            reds[tid][0] + reds[tid][1] + reds[tid][2] + reds[tid][3];
    } else if (tid < 32) {
        int kk = tid - 16;
        pss[(k0 + kk) * NPG + pg] =
            redss[kk][0] + redss[kk][1] + redss[kk][2] + redss[kk][3];
    }
}

// ---------------------------------------------------------------------------
// Kernel 2: fold 512 partials per k -> BN scale/shift. 64 blocks (one per k).
// ---------------------------------------------------------------------------
__global__ __launch_bounds__(256) void fkc_stats(
    const float* __restrict__ psum,
    const float* __restrict__ pss,
    const float* __restrict__ gamma,
    const float* __restrict__ beta,
    float* __restrict__ fin)             // [128]: scale[64], shift[64]
{
    __shared__ float sw[4], ssw[4];
    const int tid = threadIdx.x;
    const int k = blockIdx.x;

    float s  = psum[k * NPG + tid] + psum[k * NPG + 256 + tid];
    float ss = pss[k * NPG + tid]  + pss[k * NPG + 256 + tid];
#pragma unroll
    for (int off = 1; off < 64; off <<= 1) {
        s  += __shfl_xor(s,  off, 64);
        ss += __shfl_xor(ss, off, 64);
    }
    const int wv = tid >> 6;
    if ((tid & 63) == 0) { sw[wv] = s; ssw[wv] = ss; }
    __syncthreads();
    if (tid == 0) {
        float st  = sw[0] + sw[1] + sw[2] + sw[3];
        float sst = ssw[0] + ssw[1] + ssw[2] + ssw[3];
        const float invM = 1.0f / (float)(BB * NN);
        float mean = st * invM;
        float var = fmaf(-mean, mean, sst * invM);   // biased variance
        float sc = gamma[k] * rsqrtf(var + 1e-5f);
        fin[k] = sc;
        fin[KK + k] = fmaf(-mean, sc, beta[k]);
    }
}

// ---------------------------------------------------------------------------
// Kernel 3: BN + ReLU in place, float4. k uniform per block (4096 f4 per row).
// ---------------------------------------------------------------------------
__global__ __launch_bounds__(256) void fkc_apply(
    float4* __restrict__ out4,
    const float* __restrict__ fin)
{
    const int i = blockIdx.x * 256 + threadIdx.x;
    const int k = (i >> 12) & (KK - 1);      // uniform within block -> s_load
    const float sc = fin[k];
    const float sh = fin[KK + k];
    float4 v = out4[i];
    v.x = fmaxf(fmaf(v.x, sc, sh), 0.0f);
    v.y = fmaxf(fmaf(v.y, sc, sh), 0.0f);
    v.z = fmaxf(fmaf(v.z, sc, sh), 0.0f);
    v.w = fmaxf(fmaf(v.w, sc, sh), 0.0f);
    out4[i] = v;
}

extern "C" void kernel_launch(void* const* d_in, const int* in_sizes, int n_in,
                              void* d_out, int out_size, void* d_ws, size_t ws_size,
                              hipStream_t stream) {
    const float* normals = (const float*)d_in[0];
    const int*   nidx    = (const int*)d_in[1];
    const float* walpha  = (const float*)d_in[2];
    const float* wbeta   = (const float*)d_in[3];
    const float* gamma   = (const float*)d_in[4];
    const float* beta    = (const float*)d_in[5];
    float* out = (float*)d_out;
    float* ws = (float*)d_ws;

    float* psum = ws;                     // [KK*NPG] = 32768 floats
    float* pss  = ws + KK * NPG;          // [KK*NPG]
    float* fin  = ws + 2 * KK * NPG;      // [128]
    float* wxb  = ws + 2 * KK * NPG + 128;   // [256]
    float* wyb  = wxb + 256;
    float* wzb  = wyb + 256;

    fkc_prep<<<1, 256, 0, stream>>>(walpha, wbeta, wxb, wyb, wzb);
    fkc_main<<<2048, 256, 0, stream>>>(normals, nidx, wxb, wyb, wzb,
                                       out, psum, pss);
    fkc_stats<<<KK, 256, 0, stream>>>(psum, pss, gamma, beta, fin);
    fkc_apply<<<8192, 256, 0, stream>>>((float4*)out, fin);
}